// Round 10
// baseline (444.899 us; speedup 1.0000x reference)
//
#include <hip/hip_runtime.h>

#define NN 100000
#define NE 3200000
#define NG 512
#define NCB 782           // coarse buckets of 128 nodes: ceil(100000/128)
#define BN_EPS 1e-5f

typedef unsigned short u16;
typedef unsigned int u32;

__device__ __forceinline__ u16 f2bf(float f) {
    u32 u = __float_as_uint(f);
    u += 0x7FFF + ((u >> 16) & 1);  // RNE
    return (u16)(u >> 16);
}

// ================= coarse histogram (LDS-privatized) =================
__global__ __launch_bounds__(256) void k_chist(const int* __restrict__ dst, int* __restrict__ ccount) {
    __shared__ int h[NCB];
    int t = threadIdx.x;
    for (int i = t; i < NCB; i += 256) h[i] = 0;
    __syncthreads();
    int stride = gridDim.x * 256;
    for (int e = blockIdx.x * 256 + t; e < NE; e += stride)
        atomicAdd(&h[dst[e] >> 7], 1);
    __syncthreads();
    for (int i = t; i < NCB; i += 256)
        if (h[i]) atomicAdd(&ccount[i], h[i]);
}

// ========== scan coarse counts -> cbase, padded fine bases, global cursors ==========
__global__ __launch_bounds__(256) void k_cscan(const int* __restrict__ ccount, int* __restrict__ cbase,
                                               int* __restrict__ fbase, int* __restrict__ gcur) {
    __shared__ int sh[256], sh2[256];
    int t = threadIdx.x;
    int v[4], w[4];
    int s = 0, s2 = 0;
#pragma unroll
    for (int j = 0; j < 4; j++) {
        int idx = t * 4 + j;
        int c = (idx < NCB) ? ccount[idx] : 0;
        v[j] = c;
        w[j] = (idx < NCB) ? ((c + 387) & ~3) : 0;  // <=3 pad per node * 128 nodes, x4 aligned
        s += v[j]; s2 += w[j];
    }
    sh[t] = s; sh2[t] = s2;
    __syncthreads();
    for (int off = 1; off < 256; off <<= 1) {
        int x = (t >= off) ? sh[t - off] : 0;
        int x2 = (t >= off) ? sh2[t - off] : 0;
        __syncthreads();
        sh[t] += x; sh2[t] += x2;
        __syncthreads();
    }
    int run = sh[t] - s, run2 = sh2[t] - s2;
#pragma unroll
    for (int j = 0; j < 4; j++) {
        int idx = t * 4 + j;
        if (idx < NCB) { cbase[idx] = run; gcur[idx] = run; fbase[idx] = run2; }
        run += v[j]; run2 += w[j];
    }
    if (t == 255) cbase[NCB] = run;  // == NE
}

// ========== pass 1: coarse binning, block-local LDS counts + bulk reservations ==========
// P1_CHUNK=2048: 1563 blocks (6/CU) for latency hiding; d[8] avoids VGPR spill.
#define P1_CHUNK 2048
__global__ __launch_bounds__(256) void k_p1(const int* __restrict__ src, const int* __restrict__ dst,
                                            int* __restrict__ gcur, int* __restrict__ esc) {
    __shared__ int ccur[NCB];
    int t = threadIdx.x;
    int e0 = blockIdx.x * P1_CHUNK;
    for (int i = t; i < NCB; i += 256) ccur[i] = 0;
    __syncthreads();
    int n = NE - e0; if (n > P1_CHUNK) n = P1_CHUNK;
    int d[8];
#pragma unroll
    for (int j = 0; j < 8; j++) {
        int idx = t + j * 256;
        d[j] = (idx < n) ? dst[e0 + idx] : -1;
        if (d[j] >= 0) atomicAdd(&ccur[d[j] >> 7], 1);
    }
    __syncthreads();
    for (int i = t; i < NCB; i += 256) {
        int c = ccur[i];
        ccur[i] = (c > 0) ? atomicAdd(&gcur[i], c) : 0;  // one reservation per (block,bucket)
    }
    __syncthreads();
#pragma unroll
    for (int j = 0; j < 8; j++) {
        if (d[j] >= 0) {
            int idx = t + j * 256;
            int s = src[e0 + idx];
            int pos = atomicAdd(&ccur[d[j] >> 7], 1);
            esc[pos] = s | ((d[j] & 127) << 17);  // 17b src | 7b dstLocal
        }
    }
}

// ========== pass 2: fine per-node CSR within each coarse bucket; emits offs/cntp/dinv ==========
__global__ __launch_bounds__(256) void k_p2(const int* __restrict__ esc, const int* __restrict__ cbase,
                                            const int* __restrict__ fbase, int* __restrict__ esf,
                                            int* __restrict__ offs, int* __restrict__ cntp,
                                            float* __restrict__ dinv) {
    __shared__ int lcnt[128], loff[128], lcur[128];
    int t = threadIdx.x, b = blockIdx.x;
    int c0 = cbase[b], c1 = cbase[b + 1];
    if (t < 128) lcnt[t] = 0;
    __syncthreads();
    for (int i = c0 + t; i < c1; i += 256) atomicAdd(&lcnt[esc[i] >> 17], 1);
    __syncthreads();
    int p = 0, cnt = 0;
    if (t < 128) { cnt = lcnt[t]; p = (cnt + 3) & ~3; loff[t] = p; }
    __syncthreads();
    for (int off = 1; off < 128; off <<= 1) {
        int x = (t >= off && t < 128) ? loff[t - off] : 0;
        __syncthreads();
        if (t < 128) loff[t] += x;
        __syncthreads();
    }
    int fb = fbase[b];
    int node = (b << 7) + t;
    if (t < 128) {
        int o = fb + loff[t] - p;
        lcur[t] = o;
        if (node < NN) {
            offs[node] = o;
            cntp[node] = p;
            dinv[node] = rsqrtf((float)(cnt + 1));  // +1 self-loop
            for (int q = cnt; q < p; q++) esf[o + q] = NN;  // sentinel -> zero row
        }
    }
    __syncthreads();
    for (int i = c0 + t; i < c1; i += 256) {
        int rec = esc[i];
        int pos = atomicAdd(&lcur[rec >> 17], 1);
        esf[pos] = rec & 0x1FFFF;
    }
}

// ===== GEMM: hp[M][64] = bf16( (X[M][K] @ W[K][64]) * dinv[row] ) =====
template <int K>
__global__ __launch_bounds__(256) void k_gemm(const float* __restrict__ X,
                                              const float* __restrict__ W,
                                              const float* __restrict__ dinv,
                                              u16* __restrict__ hp, int M) {
    __shared__ float xs[128 * 68];
    __shared__ float ws[64 * 64];
    const int t = threadIdx.x;
    const int row0 = blockIdx.x * 128;
    const int rg = t >> 3;
    const int f0 = (t & 7) * 8;

    float acc[4][8];
#pragma unroll
    for (int j = 0; j < 4; j++)
#pragma unroll
        for (int c = 0; c < 8; c++) acc[j][c] = 0.0f;

    for (int kc = 0; kc < K; kc += 64) {
        __syncthreads();
        const float4* Wg = (const float4*)(W + (size_t)kc * 64);
        float4* ws4 = (float4*)ws;
#pragma unroll
        for (int i = 0; i < 4; i++) ws4[t + i * 256] = Wg[t + i * 256];
#pragma unroll
        for (int p = 0; p < 8; p++) {
            int rr = p * 16 + (t >> 4);
            int c4 = (t & 15) * 4;
            int row = row0 + rr;
            float4 v = make_float4(0.f, 0.f, 0.f, 0.f);
            if (row < M) v = *(const float4*)(X + (size_t)row * K + kc + c4);
            *(float4*)(&xs[rr * 68 + c4]) = v;
        }
        __syncthreads();

        for (int kk = 0; kk < 64; kk += 4) {
            float4 xv[4];
#pragma unroll
            for (int j = 0; j < 4; j++)
                xv[j] = *(const float4*)(&xs[(rg + 32 * j) * 68 + kk]);
#pragma unroll
            for (int kki = 0; kki < 4; kki++) {
                float4 w0 = *(const float4*)(&ws[(kk + kki) * 64 + f0]);
                float4 w1 = *(const float4*)(&ws[(kk + kki) * 64 + f0 + 4]);
#pragma unroll
                for (int j = 0; j < 4; j++) {
                    float a = (&xv[j].x)[kki];
                    acc[j][0] = fmaf(a, w0.x, acc[j][0]);
                    acc[j][1] = fmaf(a, w0.y, acc[j][1]);
                    acc[j][2] = fmaf(a, w0.z, acc[j][2]);
                    acc[j][3] = fmaf(a, w0.w, acc[j][3]);
                    acc[j][4] = fmaf(a, w1.x, acc[j][4]);
                    acc[j][5] = fmaf(a, w1.y, acc[j][5]);
                    acc[j][6] = fmaf(a, w1.z, acc[j][6]);
                    acc[j][7] = fmaf(a, w1.w, acc[j][7]);
                }
            }
        }
    }

#pragma unroll
    for (int j = 0; j < 4; j++) {
        int row = row0 + rg + 32 * j;
        if (row < M) {
            float di = dinv[row];
            uint4 pk;
            pk.x = (u32)f2bf(acc[j][0] * di) | ((u32)f2bf(acc[j][1] * di) << 16);
            pk.y = (u32)f2bf(acc[j][2] * di) | ((u32)f2bf(acc[j][3] * di) << 16);
            pk.z = (u32)f2bf(acc[j][4] * di) | ((u32)f2bf(acc[j][5] * di) << 16);
            pk.w = (u32)f2bf(acc[j][6] * di) | ((u32)f2bf(acc[j][7] * di) << 16);
            *(uint4*)(hp + (size_t)row * 64 + f0) = pk;
        }
    }
}

// ===== wave-per-node aggregation, half-wave split, 8 gathers in flight =====
__global__ __launch_bounds__(256) void k_agg(const u32* __restrict__ hp2,
                                             const int* __restrict__ esf,
                                             const int* __restrict__ offs,
                                             const int* __restrict__ cntp,
                                             const float* __restrict__ dinv,
                                             const float* __restrict__ bias,
                                             const float* __restrict__ gam,
                                             const float* __restrict__ bet,
                                             const float* __restrict__ rm,
                                             const float* __restrict__ rv,
                                             float* __restrict__ out) {
    const int lane = threadIdx.x & 63;
    const int half = lane >> 5;
    const int fp = lane & 31;
    const int node = (blockIdx.x * 256 + threadIdx.x) >> 6;
    if (node >= NN) return;
    const int beg = offs[node];
    const int mp = cntp[node];  // multiple of 4 (sentinel-padded)
    float ax = 0.0f, ay = 0.0f;
    for (int c = 0; c < mp; c += 64) {
        int m = mp - c;
        if (m > 64) m = 64;
        int rec = (lane < m) ? esf[beg + c + lane] : NN;
        int j = 0;
        for (; j + 16 <= m; j += 16) {  // 16 edges/iter -> 8 loads in flight
            u32 v[8];
#pragma unroll
            for (int u = 0; u < 8; u++) {
                int s = __shfl(rec, j + 2 * u + half);
                v[u] = hp2[(size_t)s * 32 + fp];
            }
#pragma unroll
            for (int u = 0; u < 8; u++) {
                ax += __uint_as_float(v[u] << 16);
                ay += __uint_as_float(v[u] & 0xFFFF0000u);
            }
        }
        for (; j < m; j += 4) {         // tail (m multiple of 4)
            int s0 = __shfl(rec, j + half);
            int s1 = __shfl(rec, j + 2 + half);
            u32 v0 = hp2[(size_t)s0 * 32 + fp];
            u32 v1 = hp2[(size_t)s1 * 32 + fp];
            ax += __uint_as_float(v0 << 16);
            ay += __uint_as_float(v0 & 0xFFFF0000u);
            ax += __uint_as_float(v1 << 16);
            ay += __uint_as_float(v1 & 0xFFFF0000u);
        }
    }
    ax += __shfl_xor(ax, 32);
    ay += __shfl_xor(ay, 32);
    u32 sv = hp2[(size_t)node * 32 + fp];
    ax += __uint_as_float(sv << 16);
    ay += __uint_as_float(sv & 0xFFFF0000u);

    const float di = dinv[node];
    const int f0 = fp * 2;
    float2 bia = *(const float2*)(bias + f0);
    float2 ga  = *(const float2*)(gam + f0);
    float2 be  = *(const float2*)(bet + f0);
    float2 rme = *(const float2*)(rm + f0);
    float2 rva = *(const float2*)(rv + f0);
    float vx = ax * di + bia.x;
    float vy = ay * di + bia.y;
    float yx = (vx - rme.x) * (ga.x * rsqrtf(rva.x + BN_EPS)) + be.x;
    float yy = (vy - rme.y) * (ga.y * rsqrtf(rva.y + BN_EPS)) + be.y;
    if (half == 0)
        *(float2*)(out + (size_t)node * 64 + f0) = make_float2(fmaxf(yx, 0.0f), fmaxf(yy, 0.0f));
}

// ===== fused mean-pool + classifier: one block per graph, batch sorted, no atomics =====
__global__ __launch_bounds__(256) void k_poolcls(const float* __restrict__ h,
                                                 const int* __restrict__ batch,
                                                 const float* __restrict__ Wc,
                                                 const float* __restrict__ bc,
                                                 float* __restrict__ out) {
    __shared__ float sh[256];
    const int g = blockIdx.x;
    const int t = threadIdx.x;
    const int lane = t & 63;
    const int wv = t >> 6;
    int lo = 0, hi = NN;
    while (lo < hi) { int mid = (lo + hi) >> 1; if (batch[mid] < g) lo = mid + 1; else hi = mid; }
    const int r0 = lo;
    hi = NN;
    while (lo < hi) { int mid = (lo + hi) >> 1; if (batch[mid] < g + 1) lo = mid + 1; else hi = mid; }
    const int r1 = lo;
    float acc = 0.0f;
    for (int r = r0 + wv; r < r1; r += 4)
        acc += h[(size_t)r * 64 + lane];
    sh[t] = acc;
    __syncthreads();
    if (wv == 0) {
        float p = sh[lane] + sh[64 + lane] + sh[128 + lane] + sh[192 + lane];
        p *= 1.0f / fmaxf((float)(r1 - r0), 1.0f);
        float c0 = p * Wc[lane * 3 + 0];
        float c1 = p * Wc[lane * 3 + 1];
        float c2 = p * Wc[lane * 3 + 2];
        for (int o = 32; o > 0; o >>= 1) {
            c0 += __shfl_xor(c0, o);
            c1 += __shfl_xor(c1, o);
            c2 += __shfl_xor(c2, o);
        }
        if (lane == 0) {
            out[g * 3 + 0] = c0 + bc[0];
            out[g * 3 + 1] = c1 + bc[1];
            out[g * 3 + 2] = c2 + bc[2];
        }
    }
}

extern "C" void kernel_launch(void* const* d_in, const int* in_sizes, int n_in,
                              void* d_out, int out_size, void* d_ws, size_t ws_size,
                              hipStream_t stream) {
    const float* x   = (const float*)d_in[0];
    const float* W1  = (const float*)d_in[1];
    const float* b1  = (const float*)d_in[2];
    const float* g1  = (const float*)d_in[3];
    const float* bt1 = (const float*)d_in[4];
    const float* rm1 = (const float*)d_in[5];
    const float* rv1 = (const float*)d_in[6];
    const float* W2  = (const float*)d_in[7];
    const float* b2  = (const float*)d_in[8];
    const float* g2  = (const float*)d_in[9];
    const float* bt2 = (const float*)d_in[10];
    const float* rm2 = (const float*)d_in[11];
    const float* rv2 = (const float*)d_in[12];
    const float* Wc  = (const float*)d_in[13];
    const float* bc  = (const float*)d_in[14];
    const int* ei    = (const int*)d_in[15];
    const int* batch = (const int*)d_in[16];
    const int* srcp = ei;
    const int* dstp = ei + NE;

    char* ws = (char*)d_ws;
    // layout preserved from round 9 (hpb at 0 — keep the alignment that sped up k_agg)
    u16*   hpb    = (u16*)(ws);                 // (NN+1)*64 bf16 = 12,800,128 B
    int*   ccount = (int*)(ws + 12800128);      // NCB
    int*   cbase  = (int*)(ws + 12803264);      // NCB+1
    int*   fbase  = (int*)(ws + 12806400);      // NCB
    int*   gcur   = (int*)(ws + 12809536);      // NCB
    int*   offs   = (int*)(ws + 12812672);      // NN
    int*   cntp   = (int*)(ws + 13212672);      // NN
    float* dinv   = (float*)(ws + 13612672);    // NN
    int*   esf    = (int*)(ws + 14012672);      // NE + 387*NCB ints (~14.0 MB)
    float* bufB   = (float*)(ws + 28052672);    // NN*64 fp32 = 25.6 MB
    int*   esc    = (int*)(ws + 28052672);      // NE ints — overlaps bufB (dead before agg1 writes)

    // ---- single init memset: sentinel zero row (128 B) + ccount (3128 B), adjacent ----
    hipMemsetAsync(hpb + (size_t)NN * 64, 0, 128 + NCB * 4, stream);

    // ---- CSR build ----
    k_chist<<<512, 256, 0, stream>>>(dstp, ccount);
    k_cscan<<<1, 256, 0, stream>>>(ccount, cbase, fbase, gcur);
    k_p1<<<(NE + P1_CHUNK - 1) / P1_CHUNK, 256, 0, stream>>>(srcp, dstp, gcur, esc);
    k_p2<<<NCB, 256, 0, stream>>>(esc, cbase, fbase, esf, offs, cntp, dinv);

    // ---- layer 1 ----
    k_gemm<128><<<(NN + 127) / 128, 256, 0, stream>>>(x, W1, dinv, hpb, NN);
    k_agg<<<(NN * 64 + 255) / 256, 256, 0, stream>>>((const u32*)hpb, esf, offs, cntp, dinv, b1, g1, bt1, rm1, rv1, bufB);

    // ---- layer 2 ----
    k_gemm<64><<<(NN + 127) / 128, 256, 0, stream>>>(bufB, W2, dinv, hpb, NN);
    k_agg<<<(NN * 64 + 255) / 256, 256, 0, stream>>>((const u32*)hpb, esf, offs, cntp, dinv, b2, g2, bt2, rm2, rv2, bufB);

    // ---- fused mean-pool + classify ----
    k_poolcls<<<NG, 256, 0, stream>>>(bufB, batch, Wc, bc, (float*)d_out);
}

// Round 11
// 394.429 us; speedup vs baseline: 1.1280x; 1.1280x over previous
//
#include <hip/hip_runtime.h>

#define NN 100000
#define NE 3200000
#define NG 512
#define NCB 782           // coarse buckets of 128 nodes: ceil(100000/128)
#define BN_EPS 1e-5f

typedef unsigned short u16;
typedef unsigned int u32;

__device__ __forceinline__ u16 f2bf(float f) {
    u32 u = __float_as_uint(f);
    u += 0x7FFF + ((u >> 16) & 1);  // RNE
    return (u16)(u >> 16);
}

// ================= coarse histogram (LDS-privatized) =================
__global__ __launch_bounds__(256) void k_chist(const int* __restrict__ dst, int* __restrict__ ccount) {
    __shared__ int h[NCB];
    int t = threadIdx.x;
    for (int i = t; i < NCB; i += 256) h[i] = 0;
    __syncthreads();
    int stride = gridDim.x * 256;
    for (int e = blockIdx.x * 256 + t; e < NE; e += stride)
        atomicAdd(&h[dst[e] >> 7], 1);
    __syncthreads();
    for (int i = t; i < NCB; i += 256)
        if (h[i]) atomicAdd(&ccount[i], h[i]);
}

// ========== scan coarse counts -> cbase, padded fine bases, global cursors ==========
__global__ __launch_bounds__(256) void k_cscan(const int* __restrict__ ccount, int* __restrict__ cbase,
                                               int* __restrict__ fbase, int* __restrict__ gcur) {
    __shared__ int sh[256], sh2[256];
    int t = threadIdx.x;
    int v[4], w[4];
    int s = 0, s2 = 0;
#pragma unroll
    for (int j = 0; j < 4; j++) {
        int idx = t * 4 + j;
        int c = (idx < NCB) ? ccount[idx] : 0;
        v[j] = c;
        w[j] = (idx < NCB) ? ((c + 387) & ~3) : 0;  // <=3 pad per node * 128 nodes, x4 aligned
        s += v[j]; s2 += w[j];
    }
    sh[t] = s; sh2[t] = s2;
    __syncthreads();
    for (int off = 1; off < 256; off <<= 1) {
        int x = (t >= off) ? sh[t - off] : 0;
        int x2 = (t >= off) ? sh2[t - off] : 0;
        __syncthreads();
        sh[t] += x; sh2[t] += x2;
        __syncthreads();
    }
    int run = sh[t] - s, run2 = sh2[t] - s2;
#pragma unroll
    for (int j = 0; j < 4; j++) {
        int idx = t * 4 + j;
        if (idx < NCB) { cbase[idx] = run; gcur[idx] = run; fbase[idx] = run2; }
        run += v[j]; run2 += w[j];
    }
    if (t == 255) cbase[NCB] = run;  // == NE
}

// ========== pass 1: coarse binning ==========
// 1024-thread blocks, 16K-edge chunks: 196 blocks x 16 waves (16 waves/CU),
// per-(block,bucket) runs ~21 edges (~84 B > cache line) to minimize
// partial-line write amplification. No register edge-cache: dst/src re-read
// in phase 3 (L3-resident).
#define P1_CHUNK 16384
__global__ __launch_bounds__(1024) void k_p1(const int* __restrict__ src, const int* __restrict__ dst,
                                             int* __restrict__ gcur, int* __restrict__ esc) {
    __shared__ int ccur[NCB];
    const int t = threadIdx.x;
    const int e0 = blockIdx.x * P1_CHUNK;
    for (int i = t; i < NCB; i += 1024) ccur[i] = 0;
    __syncthreads();
    int n = NE - e0; if (n > P1_CHUNK) n = P1_CHUNK;
    // phase 1: block-local histogram
    for (int idx = t; idx < n; idx += 1024)
        atomicAdd(&ccur[dst[e0 + idx] >> 7], 1);
    __syncthreads();
    // phase 2: one global reservation per (block,bucket)
    for (int i = t; i < NCB; i += 1024) {
        int c = ccur[i];
        ccur[i] = (c > 0) ? atomicAdd(&gcur[i], c) : 0;
    }
    __syncthreads();
    // phase 3: scatter (re-read src/dst — L3-hot)
    for (int idx = t; idx < n; idx += 1024) {
        int dd = dst[e0 + idx];
        int s = src[e0 + idx];
        int pos = atomicAdd(&ccur[dd >> 7], 1);
        esc[pos] = s | ((dd & 127) << 17);  // 17b src | 7b dstLocal
    }
}

// ========== pass 2: fine per-node CSR within each coarse bucket; emits offs/cntp/dinv ==========
__global__ __launch_bounds__(256) void k_p2(const int* __restrict__ esc, const int* __restrict__ cbase,
                                            const int* __restrict__ fbase, int* __restrict__ esf,
                                            int* __restrict__ offs, int* __restrict__ cntp,
                                            float* __restrict__ dinv) {
    __shared__ int lcnt[128], loff[128], lcur[128];
    int t = threadIdx.x, b = blockIdx.x;
    int c0 = cbase[b], c1 = cbase[b + 1];
    if (t < 128) lcnt[t] = 0;
    __syncthreads();
    for (int i = c0 + t; i < c1; i += 256) atomicAdd(&lcnt[esc[i] >> 17], 1);
    __syncthreads();
    int p = 0, cnt = 0;
    if (t < 128) { cnt = lcnt[t]; p = (cnt + 3) & ~3; loff[t] = p; }
    __syncthreads();
    for (int off = 1; off < 128; off <<= 1) {
        int x = (t >= off && t < 128) ? loff[t - off] : 0;
        __syncthreads();
        if (t < 128) loff[t] += x;
        __syncthreads();
    }
    int fb = fbase[b];
    int node = (b << 7) + t;
    if (t < 128) {
        int o = fb + loff[t] - p;
        lcur[t] = o;
        if (node < NN) {
            offs[node] = o;
            cntp[node] = p;
            dinv[node] = rsqrtf((float)(cnt + 1));  // +1 self-loop
            for (int q = cnt; q < p; q++) esf[o + q] = NN;  // sentinel -> zero row
        }
    }
    __syncthreads();
    for (int i = c0 + t; i < c1; i += 256) {
        int rec = esc[i];
        int pos = atomicAdd(&lcur[rec >> 17], 1);
        esf[pos] = rec & 0x1FFFF;
    }
}

// ===== GEMM: hp[M][64] = bf16( (X[M][K] @ W[K][64]) * dinv[row] ) =====
template <int K>
__global__ __launch_bounds__(256) void k_gemm(const float* __restrict__ X,
                                              const float* __restrict__ W,
                                              const float* __restrict__ dinv,
                                              u16* __restrict__ hp, int M) {
    __shared__ float xs[128 * 68];
    __shared__ float ws[64 * 64];
    const int t = threadIdx.x;
    const int row0 = blockIdx.x * 128;
    const int rg = t >> 3;
    const int f0 = (t & 7) * 8;

    float acc[4][8];
#pragma unroll
    for (int j = 0; j < 4; j++)
#pragma unroll
        for (int c = 0; c < 8; c++) acc[j][c] = 0.0f;

    for (int kc = 0; kc < K; kc += 64) {
        __syncthreads();
        const float4* Wg = (const float4*)(W + (size_t)kc * 64);
        float4* ws4 = (float4*)ws;
#pragma unroll
        for (int i = 0; i < 4; i++) ws4[t + i * 256] = Wg[t + i * 256];
#pragma unroll
        for (int p = 0; p < 8; p++) {
            int rr = p * 16 + (t >> 4);
            int c4 = (t & 15) * 4;
            int row = row0 + rr;
            float4 v = make_float4(0.f, 0.f, 0.f, 0.f);
            if (row < M) v = *(const float4*)(X + (size_t)row * K + kc + c4);
            *(float4*)(&xs[rr * 68 + c4]) = v;
        }
        __syncthreads();

        for (int kk = 0; kk < 64; kk += 4) {
            float4 xv[4];
#pragma unroll
            for (int j = 0; j < 4; j++)
                xv[j] = *(const float4*)(&xs[(rg + 32 * j) * 68 + kk]);
#pragma unroll
            for (int kki = 0; kki < 4; kki++) {
                float4 w0 = *(const float4*)(&ws[(kk + kki) * 64 + f0]);
                float4 w1 = *(const float4*)(&ws[(kk + kki) * 64 + f0 + 4]);
#pragma unroll
                for (int j = 0; j < 4; j++) {
                    float a = (&xv[j].x)[kki];
                    acc[j][0] = fmaf(a, w0.x, acc[j][0]);
                    acc[j][1] = fmaf(a, w0.y, acc[j][1]);
                    acc[j][2] = fmaf(a, w0.z, acc[j][2]);
                    acc[j][3] = fmaf(a, w0.w, acc[j][3]);
                    acc[j][4] = fmaf(a, w1.x, acc[j][4]);
                    acc[j][5] = fmaf(a, w1.y, acc[j][5]);
                    acc[j][6] = fmaf(a, w1.z, acc[j][6]);
                    acc[j][7] = fmaf(a, w1.w, acc[j][7]);
                }
            }
        }
    }

#pragma unroll
    for (int j = 0; j < 4; j++) {
        int row = row0 + rg + 32 * j;
        if (row < M) {
            float di = dinv[row];
            uint4 pk;
            pk.x = (u32)f2bf(acc[j][0] * di) | ((u32)f2bf(acc[j][1] * di) << 16);
            pk.y = (u32)f2bf(acc[j][2] * di) | ((u32)f2bf(acc[j][3] * di) << 16);
            pk.z = (u32)f2bf(acc[j][4] * di) | ((u32)f2bf(acc[j][5] * di) << 16);
            pk.w = (u32)f2bf(acc[j][6] * di) | ((u32)f2bf(acc[j][7] * di) << 16);
            *(uint4*)(hp + (size_t)row * 64 + f0) = pk;
        }
    }
}

// ===== wave-per-node aggregation, half-wave split, 8 gathers in flight =====
__global__ __launch_bounds__(256) void k_agg(const u32* __restrict__ hp2,
                                             const int* __restrict__ esf,
                                             const int* __restrict__ offs,
                                             const int* __restrict__ cntp,
                                             const float* __restrict__ dinv,
                                             const float* __restrict__ bias,
                                             const float* __restrict__ gam,
                                             const float* __restrict__ bet,
                                             const float* __restrict__ rm,
                                             const float* __restrict__ rv,
                                             float* __restrict__ out) {
    const int lane = threadIdx.x & 63;
    const int half = lane >> 5;
    const int fp = lane & 31;
    const int node = (blockIdx.x * 256 + threadIdx.x) >> 6;
    if (node >= NN) return;
    const int beg = offs[node];
    const int mp = cntp[node];  // multiple of 4 (sentinel-padded)
    float ax = 0.0f, ay = 0.0f;
    for (int c = 0; c < mp; c += 64) {
        int m = mp - c;
        if (m > 64) m = 64;
        int rec = (lane < m) ? esf[beg + c + lane] : NN;
        int j = 0;
        for (; j + 16 <= m; j += 16) {  // 16 edges/iter -> 8 loads in flight
            u32 v[8];
#pragma unroll
            for (int u = 0; u < 8; u++) {
                int s = __shfl(rec, j + 2 * u + half);
                v[u] = hp2[(size_t)s * 32 + fp];
            }
#pragma unroll
            for (int u = 0; u < 8; u++) {
                ax += __uint_as_float(v[u] << 16);
                ay += __uint_as_float(v[u] & 0xFFFF0000u);
            }
        }
        for (; j < m; j += 4) {         // tail (m multiple of 4)
            int s0 = __shfl(rec, j + half);
            int s1 = __shfl(rec, j + 2 + half);
            u32 v0 = hp2[(size_t)s0 * 32 + fp];
            u32 v1 = hp2[(size_t)s1 * 32 + fp];
            ax += __uint_as_float(v0 << 16);
            ay += __uint_as_float(v0 & 0xFFFF0000u);
            ax += __uint_as_float(v1 << 16);
            ay += __uint_as_float(v1 & 0xFFFF0000u);
        }
    }
    ax += __shfl_xor(ax, 32);
    ay += __shfl_xor(ay, 32);
    u32 sv = hp2[(size_t)node * 32 + fp];
    ax += __uint_as_float(sv << 16);
    ay += __uint_as_float(sv & 0xFFFF0000u);

    const float di = dinv[node];
    const int f0 = fp * 2;
    float2 bia = *(const float2*)(bias + f0);
    float2 ga  = *(const float2*)(gam + f0);
    float2 be  = *(const float2*)(bet + f0);
    float2 rme = *(const float2*)(rm + f0);
    float2 rva = *(const float2*)(rv + f0);
    float vx = ax * di + bia.x;
    float vy = ay * di + bia.y;
    float yx = (vx - rme.x) * (ga.x * rsqrtf(rva.x + BN_EPS)) + be.x;
    float yy = (vy - rme.y) * (ga.y * rsqrtf(rva.y + BN_EPS)) + be.y;
    if (half == 0)
        *(float2*)(out + (size_t)node * 64 + f0) = make_float2(fmaxf(yx, 0.0f), fmaxf(yy, 0.0f));
}

// ===== fused mean-pool + classifier: one block per graph, batch sorted, no atomics =====
__global__ __launch_bounds__(256) void k_poolcls(const float* __restrict__ h,
                                                 const int* __restrict__ batch,
                                                 const float* __restrict__ Wc,
                                                 const float* __restrict__ bc,
                                                 float* __restrict__ out) {
    __shared__ float sh[256];
    const int g = blockIdx.x;
    const int t = threadIdx.x;
    const int lane = t & 63;
    const int wv = t >> 6;
    int lo = 0, hi = NN;
    while (lo < hi) { int mid = (lo + hi) >> 1; if (batch[mid] < g) lo = mid + 1; else hi = mid; }
    const int r0 = lo;
    hi = NN;
    while (lo < hi) { int mid = (lo + hi) >> 1; if (batch[mid] < g + 1) lo = mid + 1; else hi = mid; }
    const int r1 = lo;
    float acc = 0.0f;
    for (int r = r0 + wv; r < r1; r += 4)
        acc += h[(size_t)r * 64 + lane];
    sh[t] = acc;
    __syncthreads();
    if (wv == 0) {
        float p = sh[lane] + sh[64 + lane] + sh[128 + lane] + sh[192 + lane];
        p *= 1.0f / fmaxf((float)(r1 - r0), 1.0f);
        float c0 = p * Wc[lane * 3 + 0];
        float c1 = p * Wc[lane * 3 + 1];
        float c2 = p * Wc[lane * 3 + 2];
        for (int o = 32; o > 0; o >>= 1) {
            c0 += __shfl_xor(c0, o);
            c1 += __shfl_xor(c1, o);
            c2 += __shfl_xor(c2, o);
        }
        if (lane == 0) {
            out[g * 3 + 0] = c0 + bc[0];
            out[g * 3 + 1] = c1 + bc[1];
            out[g * 3 + 2] = c2 + bc[2];
        }
    }
}

extern "C" void kernel_launch(void* const* d_in, const int* in_sizes, int n_in,
                              void* d_out, int out_size, void* d_ws, size_t ws_size,
                              hipStream_t stream) {
    const float* x   = (const float*)d_in[0];
    const float* W1  = (const float*)d_in[1];
    const float* b1  = (const float*)d_in[2];
    const float* g1  = (const float*)d_in[3];
    const float* bt1 = (const float*)d_in[4];
    const float* rm1 = (const float*)d_in[5];
    const float* rv1 = (const float*)d_in[6];
    const float* W2  = (const float*)d_in[7];
    const float* b2  = (const float*)d_in[8];
    const float* g2  = (const float*)d_in[9];
    const float* bt2 = (const float*)d_in[10];
    const float* rm2 = (const float*)d_in[11];
    const float* rv2 = (const float*)d_in[12];
    const float* Wc  = (const float*)d_in[13];
    const float* bc  = (const float*)d_in[14];
    const int* ei    = (const int*)d_in[15];
    const int* batch = (const int*)d_in[16];
    const int* srcp = ei;
    const int* dstp = ei + NE;

    char* ws = (char*)d_ws;
    // layout preserved from round 9 (hpb at 0 — keep the alignment that sped up k_agg)
    u16*   hpb    = (u16*)(ws);                 // (NN+1)*64 bf16 = 12,800,128 B
    int*   ccount = (int*)(ws + 12800128);      // NCB
    int*   cbase  = (int*)(ws + 12803264);      // NCB+1
    int*   fbase  = (int*)(ws + 12806400);      // NCB
    int*   gcur   = (int*)(ws + 12809536);      // NCB
    int*   offs   = (int*)(ws + 12812672);      // NN
    int*   cntp   = (int*)(ws + 13212672);      // NN
    float* dinv   = (float*)(ws + 13612672);    // NN
    int*   esf    = (int*)(ws + 14012672);      // NE + 387*NCB ints (~14.0 MB)
    float* bufB   = (float*)(ws + 28052672);    // NN*64 fp32 = 25.6 MB
    int*   esc    = (int*)(ws + 28052672);      // NE ints — overlaps bufB (dead before agg1 writes)

    // ---- single init memset: sentinel zero row (128 B) + ccount (3128 B), adjacent ----
    hipMemsetAsync(hpb + (size_t)NN * 64, 0, 128 + NCB * 4, stream);

    // ---- CSR build ----
    k_chist<<<512, 256, 0, stream>>>(dstp, ccount);
    k_cscan<<<1, 256, 0, stream>>>(ccount, cbase, fbase, gcur);
    k_p1<<<(NE + P1_CHUNK - 1) / P1_CHUNK, 1024, 0, stream>>>(srcp, dstp, gcur, esc);
    k_p2<<<NCB, 256, 0, stream>>>(esc, cbase, fbase, esf, offs, cntp, dinv);

    // ---- layer 1 ----
    k_gemm<128><<<(NN + 127) / 128, 256, 0, stream>>>(x, W1, dinv, hpb, NN);
    k_agg<<<(NN * 64 + 255) / 256, 256, 0, stream>>>((const u32*)hpb, esf, offs, cntp, dinv, b1, g1, bt1, rm1, rv1, bufB);

    // ---- layer 2 ----
    k_gemm<64><<<(NN + 127) / 128, 256, 0, stream>>>(bufB, W2, dinv, hpb, NN);
    k_agg<<<(NN * 64 + 255) / 256, 256, 0, stream>>>((const u32*)hpb, esf, offs, cntp, dinv, b2, g2, bt2, rm2, rv2, bufB);

    // ---- fused mean-pool + classify ----
    k_poolcls<<<NG, 256, 0, stream>>>(bufB, batch, Wc, bc, (float*)d_out);
}